// Round 3
// baseline (445.751 us; speedup 1.0000x reference)
//
#include <hip/hip_runtime.h>

// HybridQLSTM: quantum layer reduced analytically.
//   RX(x_w) then RX(th_w) merge -> per-wire angle phi_w; pre-CNOT state is a
//   product state with independent bit marginals P(1)=sin^2(phi/2).
//   CNOT(0,1),(1,2),(2,3),(3,0) act classically on basis bits:
//     b0'=a1^a2^a3, b1'=a0^a1, b2'=a0^a1^a2, b3'=a0^a1^a2^a3
//   E[(-1)^(xor S)] = prod_{w in S} cos(phi_w)  =>
//     z0=c1c2c3, z1=c0c1, z2=c0c1c2, z3=c0c1c2c3.
// phase1: xproj[row][w*4+g] = sum_k x[row][k]*W_g[k][w] + b_g[w] + th_g[w]
// phase2: sequential scan over T; per batch element 4 lanes (lane = wire);
//         quad broadcasts via DPP quad_perm (VALU pipe, ~2cyc) not ds_bpermute.

#define T_DIM 256
#define B_DIM 1024
#define D_DIM 128
#define NROW (T_DIM * B_DIM)

__device__ __forceinline__ float fast_cos(float x) {
    // hw v_cos_f32 takes revolutions; reduce with floor to stay in-domain.
    float r = x * 0.15915494309189535f;
    r = r - floorf(r);
    return __builtin_amdgcn_cosf(r);
}

template <int J>
__device__ __forceinline__ float quad_bcast(float v) {
    // broadcast lane (quad_base + J) to all 4 lanes of the quad (DPP quad_perm)
    int i = __builtin_bit_cast(int, v);
    int r = __builtin_amdgcn_update_dpp(i, i, J * 0x55, 0xF, 0xF, true);
    return __builtin_bit_cast(float, r);
}

__global__ __launch_bounds__(64) void qlstm_phase1(
    const float* __restrict__ x,
    const float* __restrict__ Wf, const float* __restrict__ bf, const float* __restrict__ thf,
    const float* __restrict__ Wi, const float* __restrict__ bi, const float* __restrict__ thi,
    const float* __restrict__ Wu, const float* __restrict__ bu, const float* __restrict__ thu,
    const float* __restrict__ Wo, const float* __restrict__ bo, const float* __restrict__ tho,
    float* __restrict__ xproj)
{
    __shared__ float Wl[128 * 16];     // Wl[k*16 + w*4 + g]
    __shared__ float bth[16];          // b+th, [w*4+g]
    __shared__ float xl[64 * 132];     // 64 rows, pitch 132 (stride % 32 banks == 4)

    const int tid = threadIdx.x;
    const float* Wp[4] = {Wf, Wi, Wu, Wo};

    #pragma unroll
    for (int g = 0; g < 4; ++g) {
        const float* W = Wp[g];
        for (int idx = tid; idx < 512; idx += 64) {
            int k = idx >> 2, w = idx & 3;
            Wl[k * 16 + w * 4 + g] = W[k * 4 + w];
        }
    }
    if (tid < 16) {
        int g = tid & 3, w = tid >> 2;
        float bv, tv;
        if (g == 0)      { bv = bf[w]; tv = thf[w]; }
        else if (g == 1) { bv = bi[w]; tv = thi[w]; }
        else if (g == 2) { bv = bu[w]; tv = thu[w]; }
        else             { bv = bo[w]; tv = tho[w]; }
        bth[w * 4 + g] = bv + tv;
    }

    const int row0 = blockIdx.x * 64;
    const float4* xg = (const float4*)(x + (size_t)row0 * 128);
    for (int i = tid; i < 2048; i += 64) {
        int r = i >> 5, kk = i & 31;
        *(float4*)&xl[r * 132 + kk * 4] = xg[i];
    }
    __syncthreads();

    const int rg = tid >> 2;   // row group 0..15, handles rows rg + 16*r
    const int cg = tid & 3;    // wire w = cg; cols cg*4 .. cg*4+3 (gate = low idx)

    float acc[4][4];
    #pragma unroll
    for (int r = 0; r < 4; ++r)
        #pragma unroll
        for (int c = 0; c < 4; ++c) acc[r][c] = 0.f;

    for (int kk = 0; kk < 32; ++kk) {
        float4 wv[4];
        #pragma unroll
        for (int j = 0; j < 4; ++j)
            wv[j] = *(const float4*)&Wl[(kk * 4 + j) * 16 + cg * 4];
        #pragma unroll
        for (int r = 0; r < 4; ++r) {
            float4 xv = *(const float4*)&xl[(rg + r * 16) * 132 + kk * 4];
            float xs[4] = {xv.x, xv.y, xv.z, xv.w};
            float* wf0 = (float*)&wv[0];
            float* wf1 = (float*)&wv[1];
            float* wf2 = (float*)&wv[2];
            float* wf3 = (float*)&wv[3];
            #pragma unroll
            for (int c = 0; c < 4; ++c) {
                acc[r][c] += xs[0] * wf0[c];
                acc[r][c] += xs[1] * wf1[c];
                acc[r][c] += xs[2] * wf2[c];
                acc[r][c] += xs[3] * wf3[c];
            }
        }
    }

    float4 bv = *(const float4*)&bth[cg * 4];
    float bs[4] = {bv.x, bv.y, bv.z, bv.w};
    #pragma unroll
    for (int r = 0; r < 4; ++r) {
        int row = row0 + rg + r * 16;
        float4 o;
        o.x = acc[r][0] + bs[0];
        o.y = acc[r][1] + bs[1];
        o.z = acc[r][2] + bs[2];
        o.w = acc[r][3] + bs[3];
        ((float4*)xproj)[row * 4 + cg] = o;
    }
}

__global__ __launch_bounds__(64) void qlstm_phase2(
    const float* __restrict__ xproj,
    const float* __restrict__ Wf, const float* __restrict__ Wi,
    const float* __restrict__ Wu, const float* __restrict__ Wo,
    float* __restrict__ out)
{
    const int tid = threadIdx.x;           // block = 1 wave of 64
    const int w = tid & 3;                 // wire
    const int b = (blockIdx.x * 64 + tid) >> 2;

    // Wh[g][j] = W_g[128+j][w]  (recurrent part)
    float Wh[4][4];
    #pragma unroll
    for (int j = 0; j < 4; ++j) {
        Wh[0][j] = Wf[(128 + j) * 4 + w];
        Wh[1][j] = Wi[(128 + j) * 4 + w];
        Wh[2][j] = Wu[(128 + j) * 4 + w];
        Wh[3][j] = Wo[(128 + j) * 4 + w];
    }

    float h[4] = {0.f, 0.f, 0.f, 0.f};
    float c = 0.f, hw = 0.f;

    const float4* xp4 = (const float4*)xproj;
    // prefetch distance 2: covers L2/L3 latency beyond one step's chain
    float4 nxt0 = xp4[(0 * B_DIM + b) * 4 + w];
    float4 nxt1 = xp4[(1 * B_DIM + b) * 4 + w];

    for (int t = 0; t < T_DIM; ++t) {
        float4 xp = nxt0;
        nxt0 = nxt1;
        int tn = (t + 2 < T_DIM) ? (t + 2) : (T_DIM - 1);
        nxt1 = xp4[(tn * B_DIM + b) * 4 + w];

        float xps[4] = {xp.x, xp.y, xp.z, xp.w};
        float z[4];
        #pragma unroll
        for (int g = 0; g < 4; ++g) {
            float a = (xps[g] + h[0] * Wh[g][0] + h[1] * Wh[g][1])
                    + (h[2] * Wh[g][2] + h[3] * Wh[g][3]);
            float cw = fast_cos(a);
            float c0 = quad_bcast<0>(cw);
            float c1 = quad_bcast<1>(cw);
            float c2 = quad_bcast<2>(cw);
            float c3 = quad_bcast<3>(cw);
            float p01   = c0 * c1;
            float p012  = p01 * c2;
            float p0123 = p012 * c3;
            float p123  = c1 * c2 * c3;
            z[g] = (w == 0) ? p123 : (w == 1) ? p01 : (w == 2) ? p012 : p0123;
        }

        float fg = 1.f / (1.f + __expf(-z[0]));
        float ig = 1.f / (1.f + __expf(-z[1]));
        float ug = 1.f - 2.f / (__expf(2.f * z[2]) + 1.f);
        float og = 1.f / (1.f + __expf(-z[3]));

        c = fg * c + ig * ug;
        float ct = 1.f - 2.f / (__expf(2.f * c) + 1.f);
        hw = og * ct;

        out[(t * B_DIM + b) * 4 + w] = hw;

        h[0] = quad_bcast<0>(hw);
        h[1] = quad_bcast<1>(hw);
        h[2] = quad_bcast<2>(hw);
        h[3] = quad_bcast<3>(hw);
    }

    out[T_DIM * B_DIM * 4 + b * 4 + w] = hw;                  // hx
    out[T_DIM * B_DIM * 4 + B_DIM * 4 + b * 4 + w] = c;       // cx
}

extern "C" void kernel_launch(void* const* d_in, const int* in_sizes, int n_in,
                              void* d_out, int out_size, void* d_ws, size_t ws_size,
                              hipStream_t stream) {
    const float* x   = (const float*)d_in[0];
    const float* Wf  = (const float*)d_in[1];
    const float* bf  = (const float*)d_in[2];
    const float* thf = (const float*)d_in[3];
    const float* Wi  = (const float*)d_in[4];
    const float* bi  = (const float*)d_in[5];
    const float* thi = (const float*)d_in[6];
    const float* Wu  = (const float*)d_in[7];
    const float* bu  = (const float*)d_in[8];
    const float* thu = (const float*)d_in[9];
    const float* Wo  = (const float*)d_in[10];
    const float* bo  = (const float*)d_in[11];
    const float* tho = (const float*)d_in[12];

    float* xproj = (float*)d_ws;            // 262144 * 16 * 4B = 16.8 MB
    float* out   = (float*)d_out;

    qlstm_phase1<<<NROW / 64, 64, 0, stream>>>(x, Wf, bf, thf, Wi, bi, thi,
                                               Wu, bu, thu, Wo, bo, tho, xproj);
    qlstm_phase2<<<B_DIM * 4 / 64, 64, 0, stream>>>(xproj, Wf, Wi, Wu, Wo, out);
}

// Round 9
// 326.323 us; speedup vs baseline: 1.3660x; 1.3660x over previous
//
#include <hip/hip_runtime.h>

// HybridQLSTM: quantum layer reduced analytically.
//   RX(x_w) then RX(th_w) merge -> per-wire angle phi_w; product state with
//   independent bit marginals. CNOT(0,1),(1,2),(2,3),(3,0) act classically:
//     z0=c1c2c3, z1=c0c1, z2=c0c1c2, z3=c0c1c2c3,  c_w = cos(phi_w).
// phase1: xproj[row][w*4+g] = (x[row]@W_g + b_g + th_g)_w / (2pi)  (revolutions)
//         coalesced global->LDS staging; quad-per-row compute (lane = wire,
//         x reads quad-broadcast, W reads 4-addr wave-broadcast: conflict-free)
// phase2: sequential scan over T; 4 lanes per batch element (lane = wire);
//         quad broadcasts via DPP quad_perm; v_rcp instead of IEEE divide.

#define T_DIM 256
#define B_DIM 1024
#define D_DIM 128
#define NROW (T_DIM * B_DIM)
#define INV2PI 0.15915494309189535f

__device__ __forceinline__ float fast_cos_rev(float r) {
    // input pre-scaled to revolutions; reduce to [0,1) for v_cos domain
    r = r - floorf(r);
    return __builtin_amdgcn_cosf(r);
}

__device__ __forceinline__ float fast_rcp(float x) {
    return __builtin_amdgcn_rcpf(x);     // v_rcp_f32, ~1 ulp
}

template <int J>
__device__ __forceinline__ float quad_bcast(float v) {
    // broadcast lane (quad_base + J) to all 4 lanes of the quad (DPP quad_perm)
    int i = __builtin_bit_cast(int, v);
    int r = __builtin_amdgcn_update_dpp(i, i, J * 0x55, 0xF, 0xF, true);
    return __builtin_bit_cast(float, r);
}

__global__ __launch_bounds__(256) void qlstm_phase1(
    const float* __restrict__ x,
    const float* __restrict__ Wf, const float* __restrict__ bf, const float* __restrict__ thf,
    const float* __restrict__ Wi, const float* __restrict__ bi, const float* __restrict__ thi,
    const float* __restrict__ Wu, const float* __restrict__ bu, const float* __restrict__ thu,
    const float* __restrict__ Wo, const float* __restrict__ bo, const float* __restrict__ tho,
    float* __restrict__ xproj)
{
    __shared__ float Wc[128 * 16];     // Wc[k*16 + w*4 + g] = W_g[k][w]/(2pi)
    __shared__ float bth[16];          // (b+th)/(2pi), [w*4+g]
    __shared__ float xl[64 * 132];     // subtile: 64 rows, pitch 132 floats

    const int tid = threadIdx.x;

    // pack Wc (8 KB) + bth once per block; global reads are L1/L2-hot
    for (int e = tid; e < 2048; e += 256) {
        int k = e >> 4, w = (e >> 2) & 3, g = e & 3;
        const float* W = (g == 0) ? Wf : (g == 1) ? Wi : (g == 2) ? Wu : Wo;
        Wc[e] = W[k * 4 + w] * INV2PI;
    }
    if (tid < 16) {
        int w = tid >> 2, g = tid & 3;
        float bv = (g == 0) ? bf[w] : (g == 1) ? bi[w] : (g == 2) ? bu[w] : bo[w];
        float tv = (g == 0) ? thf[w] : (g == 1) ? thi[w] : (g == 2) ? thu[w] : tho[w];
        bth[tid] = (bv + tv) * INV2PI;
    }

    const int rowq = tid >> 2;   // quad id = row within subtile (0..63)
    const int p    = tid & 3;    // lane in quad = wire

    for (int sub = 0; sub < 4; ++sub) {
        __syncthreads();         // xl reusable (also covers Wc on sub=0)

        // stage 64 rows (32 KB) coalesced: 8 x dwordx4 per thread
        const int rbase = blockIdx.x * 256 + sub * 64;
        const float4* __restrict__ src = (const float4*)x + (size_t)rbase * 32;
        #pragma unroll
        for (int it = 0; it < 8; ++it) {
            int idx = it * 256 + tid;            // 0..2047
            int r = idx >> 5, c4 = idx & 31;
            *(float4*)&xl[r * 132 + c4 * 4] = src[idx];
        }
        __syncthreads();

        // compute: quad owns row `rowq`; lane p -> wire p, gates 0..3
        float acc0 = bth[p * 4 + 0];
        float acc1 = bth[p * 4 + 1];
        float acc2 = bth[p * 4 + 2];
        float acc3 = bth[p * 4 + 3];

        #pragma unroll 8
        for (int kk = 0; kk < 32; ++kk) {
            float4 xv = *(const float4*)&xl[rowq * 132 + kk * 4];  // quad-bcast
            float xs[4] = {xv.x, xv.y, xv.z, xv.w};
            #pragma unroll
            for (int c = 0; c < 4; ++c) {
                // 4 unique 16B addrs across wave -> bank-conflict-free bcast
                float4 wv = *(const float4*)&Wc[(kk * 4 + c) * 16 + p * 4];
                acc0 += xs[c] * wv.x;
                acc1 += xs[c] * wv.y;
                acc2 += xs[c] * wv.z;
                acc3 += xs[c] * wv.w;
            }
        }

        const int row = rbase + rowq;
        ((float4*)xproj)[row * 4 + p] = make_float4(acc0, acc1, acc2, acc3);
    }
}

__global__ __launch_bounds__(64) void qlstm_phase2(
    const float* __restrict__ xproj,
    const float* __restrict__ Wf, const float* __restrict__ Wi,
    const float* __restrict__ Wu, const float* __restrict__ Wo,
    float* __restrict__ out)
{
    const int tid = threadIdx.x;           // block = 1 wave of 64
    const int w = tid & 3;                 // wire
    const int b = (blockIdx.x * 64 + tid) >> 2;

    // Wh[g][j] = W_g[128+j][w] / (2pi)  (recurrent rows, vectorized load)
    float Wh[4][4];
    {
        const float4* Wf4 = (const float4*)(Wf + 512);  // rows 128..131
        const float4* Wi4 = (const float4*)(Wi + 512);
        const float4* Wu4 = (const float4*)(Wu + 512);
        const float4* Wo4 = (const float4*)(Wo + 512);
        #pragma unroll
        for (int j = 0; j < 4; ++j) {
            float4 a = Wf4[j], bq = Wi4[j], cq = Wu4[j], d = Wo4[j];
            const float* af = (const float*)&a;
            const float* bf_ = (const float*)&bq;
            const float* cf = (const float*)&cq;
            const float* df = (const float*)&d;
            Wh[0][j] = af[w] * INV2PI;
            Wh[1][j] = bf_[w] * INV2PI;
            Wh[2][j] = cf[w] * INV2PI;
            Wh[3][j] = df[w] * INV2PI;
        }
    }

    float h[4] = {0.f, 0.f, 0.f, 0.f};
    float c = 0.f, hw = 0.f;

    const float4* __restrict__ xp4 = (const float4*)xproj;
    // prefetch distance 3: covers L3-hit latency beyond the step chain
    float4 nxt0 = xp4[(0 * B_DIM + b) * 4 + w];
    float4 nxt1 = xp4[(1 * B_DIM + b) * 4 + w];
    float4 nxt2 = xp4[(2 * B_DIM + b) * 4 + w];

    for (int t = 0; t < T_DIM; ++t) {
        float4 xp = nxt0;
        nxt0 = nxt1;
        nxt1 = nxt2;
        int tn = (t + 3 < T_DIM) ? (t + 3) : (T_DIM - 1);
        nxt2 = xp4[(tn * B_DIM + b) * 4 + w];

        float xps[4] = {xp.x, xp.y, xp.z, xp.w};
        float z[4];
        #pragma unroll
        for (int g = 0; g < 4; ++g) {
            float a = (xps[g] + h[0] * Wh[g][0] + h[1] * Wh[g][1])
                    + (h[2] * Wh[g][2] + h[3] * Wh[g][3]);
            float cw = fast_cos_rev(a);
            float c0 = quad_bcast<0>(cw);
            float c1 = quad_bcast<1>(cw);
            float c2 = quad_bcast<2>(cw);
            float c3 = quad_bcast<3>(cw);
            float p01   = c0 * c1;
            float p012  = p01 * c2;
            float p0123 = p012 * c3;
            float p123  = c1 * c2 * c3;
            z[g] = (w == 0) ? p123 : (w == 1) ? p01 : (w == 2) ? p012 : p0123;
        }

        // gates via v_rcp (no IEEE divide sequences on the serial chain)
        float fg = fast_rcp(1.f + __expf(-z[0]));
        float ig = fast_rcp(1.f + __expf(-z[1]));
        float ug = 1.f - 2.f * fast_rcp(__expf(2.f * z[2]) + 1.f);
        float og = fast_rcp(1.f + __expf(-z[3]));

        c = fg * c + ig * ug;
        float ct = 1.f - 2.f * fast_rcp(__expf(2.f * c) + 1.f);
        hw = og * ct;

        out[(t * B_DIM + b) * 4 + w] = hw;

        h[0] = quad_bcast<0>(hw);
        h[1] = quad_bcast<1>(hw);
        h[2] = quad_bcast<2>(hw);
        h[3] = quad_bcast<3>(hw);
    }

    out[T_DIM * B_DIM * 4 + b * 4 + w] = hw;                  // hx
    out[T_DIM * B_DIM * 4 + B_DIM * 4 + b * 4 + w] = c;       // cx
}

extern "C" void kernel_launch(void* const* d_in, const int* in_sizes, int n_in,
                              void* d_out, int out_size, void* d_ws, size_t ws_size,
                              hipStream_t stream) {
    const float* x   = (const float*)d_in[0];
    const float* Wf  = (const float*)d_in[1];
    const float* bf  = (const float*)d_in[2];
    const float* thf = (const float*)d_in[3];
    const float* Wi  = (const float*)d_in[4];
    const float* bi  = (const float*)d_in[5];
    const float* thi = (const float*)d_in[6];
    const float* Wu  = (const float*)d_in[7];
    const float* bu  = (const float*)d_in[8];
    const float* thu = (const float*)d_in[9];
    const float* Wo  = (const float*)d_in[10];
    const float* bo  = (const float*)d_in[11];
    const float* tho = (const float*)d_in[12];

    float* xproj = (float*)d_ws;            // 262144 * 16 * 4B = 16.8 MB
    float* out   = (float*)d_out;

    qlstm_phase1<<<NROW / 256, 256, 0, stream>>>(x, Wf, bf, thf, Wi, bi, thi,
                                                 Wu, bu, thu, Wo, bo, tho, xproj);
    qlstm_phase2<<<B_DIM * 4 / 64, 64, 0, stream>>>(xproj, Wf, Wi, Wu, Wo, out);
}

// Round 11
// 323.695 us; speedup vs baseline: 1.3771x; 1.0081x over previous
//
#include <hip/hip_runtime.h>

// HybridQLSTM: quantum layer reduced analytically.
//   RX(x_w) then RX(th_w) merge -> per-wire angle phi_w; product state with
//   independent bit marginals. CNOT(0,1),(1,2),(2,3),(3,0) act classically:
//     z0=c1c2c3, z1=c0c1, z2=c0c1c2, z3=c0c1c2c3,  c_w = cos(phi_w).
// phase1: xproj[row][w*4+g] = (x[row]@W_g + b_g + th_g)_w / (2pi)  (revolutions)
//         coalesced global->LDS staging; quad-per-row compute (lane = wire,
//         x reads quad-broadcast, W reads 4-addr wave-broadcast: conflict-free)
// phase2: sequential scan over T; 4 lanes per batch element (lane = wire);
//         quad broadcasts via DPP quad_perm; v_rcp instead of IEEE divide.
//         NOTE (r9 post-mortem): VGPR_Count=24 + VALUBusy 3% + 975 cyc/step
//         => spill on the serial chain. Fixes: no runtime-indexed locals
//         (rule #20), __launch_bounds__(64,1) for full VGPR budget.

#define T_DIM 256
#define B_DIM 1024
#define D_DIM 128
#define NROW (T_DIM * B_DIM)
#define INV2PI 0.15915494309189535f

__device__ __forceinline__ float fast_cos_rev(float r) {
    // input pre-scaled to revolutions; reduce to [0,1) for v_cos domain
    r = r - floorf(r);
    return __builtin_amdgcn_cosf(r);
}

__device__ __forceinline__ float fast_rcp(float x) {
    return __builtin_amdgcn_rcpf(x);     // v_rcp_f32, ~1 ulp
}

template <int J>
__device__ __forceinline__ float quad_bcast(float v) {
    // broadcast lane (quad_base + J) to all 4 lanes of the quad (DPP quad_perm)
    int i = __builtin_bit_cast(int, v);
    int r = __builtin_amdgcn_update_dpp(i, i, J * 0x55, 0xF, 0xF, true);
    return __builtin_bit_cast(float, r);
}

__global__ __launch_bounds__(256) void qlstm_phase1(
    const float* __restrict__ x,
    const float* __restrict__ Wf, const float* __restrict__ bf, const float* __restrict__ thf,
    const float* __restrict__ Wi, const float* __restrict__ bi, const float* __restrict__ thi,
    const float* __restrict__ Wu, const float* __restrict__ bu, const float* __restrict__ thu,
    const float* __restrict__ Wo, const float* __restrict__ bo, const float* __restrict__ tho,
    float* __restrict__ xproj)
{
    __shared__ float Wc[128 * 16];     // Wc[k*16 + w*4 + g] = W_g[k][w]/(2pi)
    __shared__ float bth[16];          // (b+th)/(2pi), [w*4+g]
    __shared__ float xl[64 * 132];     // subtile: 64 rows, pitch 132 floats

    const int tid = threadIdx.x;

    // pack Wc (8 KB) + bth once per block; global reads are L1/L2-hot
    for (int e = tid; e < 2048; e += 256) {
        int k = e >> 4, w = (e >> 2) & 3, g = e & 3;
        const float* W = (g == 0) ? Wf : (g == 1) ? Wi : (g == 2) ? Wu : Wo;
        Wc[e] = W[k * 4 + w] * INV2PI;
    }
    if (tid < 16) {
        int w = tid >> 2, g = tid & 3;
        float bv = (g == 0) ? bf[w] : (g == 1) ? bi[w] : (g == 2) ? bu[w] : bo[w];
        float tv = (g == 0) ? thf[w] : (g == 1) ? thi[w] : (g == 2) ? thu[w] : tho[w];
        bth[tid] = (bv + tv) * INV2PI;
    }

    const int rowq = tid >> 2;   // quad id = row within subtile (0..63)
    const int p    = tid & 3;    // lane in quad = wire

    for (int sub = 0; sub < 4; ++sub) {
        __syncthreads();         // xl reusable (also covers Wc on sub=0)

        // stage 64 rows (32 KB) coalesced: 8 x dwordx4 per thread
        const int rbase = blockIdx.x * 256 + sub * 64;
        const float4* __restrict__ src = (const float4*)x + (size_t)rbase * 32;
        #pragma unroll
        for (int it = 0; it < 8; ++it) {
            int idx = it * 256 + tid;            // 0..2047
            int r = idx >> 5, c4 = idx & 31;
            *(float4*)&xl[r * 132 + c4 * 4] = src[idx];
        }
        __syncthreads();

        // compute: quad owns row `rowq`; lane p -> wire p, gates 0..3
        float acc0 = bth[p * 4 + 0];
        float acc1 = bth[p * 4 + 1];
        float acc2 = bth[p * 4 + 2];
        float acc3 = bth[p * 4 + 3];

        #pragma unroll 8
        for (int kk = 0; kk < 32; ++kk) {
            float4 xv = *(const float4*)&xl[rowq * 132 + kk * 4];  // quad-bcast
            float xs[4] = {xv.x, xv.y, xv.z, xv.w};
            #pragma unroll
            for (int c = 0; c < 4; ++c) {
                // 4 unique 16B addrs across wave -> bank-conflict-free bcast
                float4 wv = *(const float4*)&Wc[(kk * 4 + c) * 16 + p * 4];
                acc0 += xs[c] * wv.x;
                acc1 += xs[c] * wv.y;
                acc2 += xs[c] * wv.z;
                acc3 += xs[c] * wv.w;
            }
        }

        const int row = rbase + rowq;
        ((float4*)xproj)[row * 4 + p] = make_float4(acc0, acc1, acc2, acc3);
    }
}

__global__ __launch_bounds__(64, 1) void qlstm_phase2(
    const float* __restrict__ xproj,
    const float* __restrict__ Wf, const float* __restrict__ Wi,
    const float* __restrict__ Wu, const float* __restrict__ Wo,
    float* __restrict__ out)
{
    const int tid = threadIdx.x;           // block = 1 wave of 64
    const int w = tid & 3;                 // wire
    const int b = (blockIdx.x * 64 + tid) >> 2;

    // Wh[g][j] = W_g[128+j][w] / (2pi)  — direct per-lane loads, no
    // runtime-indexed locals (rule #20: those go to scratch).
    float Wh[4][4];
    #pragma unroll
    for (int j = 0; j < 4; ++j) {
        Wh[0][j] = Wf[(128 + j) * 4 + w] * INV2PI;
        Wh[1][j] = Wi[(128 + j) * 4 + w] * INV2PI;
        Wh[2][j] = Wu[(128 + j) * 4 + w] * INV2PI;
        Wh[3][j] = Wo[(128 + j) * 4 + w] * INV2PI;
    }

    float h[4] = {0.f, 0.f, 0.f, 0.f};
    float c = 0.f, hw = 0.f;

    const float4* __restrict__ xp4 = (const float4*)xproj;
    // prefetch distance 3: covers L2/L3 latency beyond the step chain
    float4 nxt0 = xp4[(0 * B_DIM + b) * 4 + w];
    float4 nxt1 = xp4[(1 * B_DIM + b) * 4 + w];
    float4 nxt2 = xp4[(2 * B_DIM + b) * 4 + w];

    for (int t = 0; t < T_DIM; ++t) {
        float4 xp = nxt0;
        nxt0 = nxt1;
        nxt1 = nxt2;
        int tn = (t + 3 < T_DIM) ? (t + 3) : (T_DIM - 1);
        nxt2 = xp4[(tn * B_DIM + b) * 4 + w];

        float xps[4] = {xp.x, xp.y, xp.z, xp.w};
        float z[4];
        #pragma unroll
        for (int g = 0; g < 4; ++g) {
            float a = (xps[g] + h[0] * Wh[g][0] + h[1] * Wh[g][1])
                    + (h[2] * Wh[g][2] + h[3] * Wh[g][3]);
            float cw = fast_cos_rev(a);
            float c0 = quad_bcast<0>(cw);
            float c1 = quad_bcast<1>(cw);
            float c2 = quad_bcast<2>(cw);
            float c3 = quad_bcast<3>(cw);
            float p01   = c0 * c1;
            float p012  = p01 * c2;
            float p0123 = p012 * c3;
            float p123  = c1 * c2 * c3;
            z[g] = (w == 0) ? p123 : (w == 1) ? p01 : (w == 2) ? p012 : p0123;
        }

        // gates via v_rcp (no IEEE divide sequences on the serial chain)
        float fg = fast_rcp(1.f + __expf(-z[0]));
        float ig = fast_rcp(1.f + __expf(-z[1]));
        float ug = 1.f - 2.f * fast_rcp(__expf(2.f * z[2]) + 1.f);
        float og = fast_rcp(1.f + __expf(-z[3]));

        c = fg * c + ig * ug;
        float ct = 1.f - 2.f * fast_rcp(__expf(2.f * c) + 1.f);
        hw = og * ct;

        out[(t * B_DIM + b) * 4 + w] = hw;

        h[0] = quad_bcast<0>(hw);
        h[1] = quad_bcast<1>(hw);
        h[2] = quad_bcast<2>(hw);
        h[3] = quad_bcast<3>(hw);
    }

    out[T_DIM * B_DIM * 4 + b * 4 + w] = hw;                  // hx
    out[T_DIM * B_DIM * 4 + B_DIM * 4 + b * 4 + w] = c;       // cx
}

extern "C" void kernel_launch(void* const* d_in, const int* in_sizes, int n_in,
                              void* d_out, int out_size, void* d_ws, size_t ws_size,
                              hipStream_t stream) {
    const float* x   = (const float*)d_in[0];
    const float* Wf  = (const float*)d_in[1];
    const float* bf  = (const float*)d_in[2];
    const float* thf = (const float*)d_in[3];
    const float* Wi  = (const float*)d_in[4];
    const float* bi  = (const float*)d_in[5];
    const float* thi = (const float*)d_in[6];
    const float* Wu  = (const float*)d_in[7];
    const float* bu  = (const float*)d_in[8];
    const float* thu = (const float*)d_in[9];
    const float* Wo  = (const float*)d_in[10];
    const float* bo  = (const float*)d_in[11];
    const float* tho = (const float*)d_in[12];

    float* xproj = (float*)d_ws;            // 262144 * 16 * 4B = 16.8 MB
    float* out   = (float*)d_out;

    qlstm_phase1<<<NROW / 256, 256, 0, stream>>>(x, Wf, bf, thf, Wi, bi, thi,
                                                 Wu, bu, thu, Wo, bo, tho, xproj);
    qlstm_phase2<<<B_DIM * 4 / 64, 64, 0, stream>>>(xproj, Wf, Wi, Wu, Wo, out);
}

// Round 12
// 312.631 us; speedup vs baseline: 1.4258x; 1.0354x over previous
//
#include <hip/hip_runtime.h>

// HybridQLSTM: quantum layer reduced analytically.
//   z0=c1c2c3, z1=c0c1, z2=c0c1c2, z3=c0c1c2c3,  c_w = cos(phi_w).
// phase1: xproj[row][w*4+g] = (x[row]@W_g + b_g + th_g)_w / (2pi)  (revolutions)
// phase2: serial scan over T; 4 lanes per batch (lane = wire); DPP quad
//         broadcasts; v_rcp gates; 4-slot software pipeline with NAMED
//         scalar state (r11 post-mortem: reg-copy rotation forced a vmcnt
//         wait on the newest load every step => ~1-step effective prefetch;
//         VGPR=24 shows state never lived in registers).

#define T_DIM 256
#define B_DIM 1024
#define D_DIM 128
#define NROW (T_DIM * B_DIM)
#define INV2PI 0.15915494309189535f

__device__ __forceinline__ float fast_cos_rev(float r) {
    r = r - floorf(r);
    return __builtin_amdgcn_cosf(r);
}

__device__ __forceinline__ float fast_rcp(float x) {
    return __builtin_amdgcn_rcpf(x);
}

template <int J>
__device__ __forceinline__ float quad_bcast(float v) {
    int i = __builtin_bit_cast(int, v);
    int r = __builtin_amdgcn_update_dpp(i, i, J * 0x55, 0xF, 0xF, true);
    return __builtin_bit_cast(float, r);
}

__global__ __launch_bounds__(256) void qlstm_phase1(
    const float* __restrict__ x,
    const float* __restrict__ Wf, const float* __restrict__ bf, const float* __restrict__ thf,
    const float* __restrict__ Wi, const float* __restrict__ bi, const float* __restrict__ thi,
    const float* __restrict__ Wu, const float* __restrict__ bu, const float* __restrict__ thu,
    const float* __restrict__ Wo, const float* __restrict__ bo, const float* __restrict__ tho,
    float* __restrict__ xproj)
{
    __shared__ float Wc[128 * 16];
    __shared__ float bth[16];
    __shared__ float xl[64 * 132];

    const int tid = threadIdx.x;

    for (int e = tid; e < 2048; e += 256) {
        int k = e >> 4, w = (e >> 2) & 3, g = e & 3;
        const float* W = (g == 0) ? Wf : (g == 1) ? Wi : (g == 2) ? Wu : Wo;
        Wc[e] = W[k * 4 + w] * INV2PI;
    }
    if (tid < 16) {
        int w = tid >> 2, g = tid & 3;
        float bv = (g == 0) ? bf[w] : (g == 1) ? bi[w] : (g == 2) ? bu[w] : bo[w];
        float tv = (g == 0) ? thf[w] : (g == 1) ? thi[w] : (g == 2) ? thu[w] : tho[w];
        bth[tid] = (bv + tv) * INV2PI;
    }

    const int rowq = tid >> 2;
    const int p    = tid & 3;

    for (int sub = 0; sub < 4; ++sub) {
        __syncthreads();

        const int rbase = blockIdx.x * 256 + sub * 64;
        const float4* __restrict__ src = (const float4*)x + (size_t)rbase * 32;
        #pragma unroll
        for (int it = 0; it < 8; ++it) {
            int idx = it * 256 + tid;
            int r = idx >> 5, c4 = idx & 31;
            *(float4*)&xl[r * 132 + c4 * 4] = src[idx];
        }
        __syncthreads();

        float acc0 = bth[p * 4 + 0];
        float acc1 = bth[p * 4 + 1];
        float acc2 = bth[p * 4 + 2];
        float acc3 = bth[p * 4 + 3];

        #pragma unroll 8
        for (int kk = 0; kk < 32; ++kk) {
            float4 xv = *(const float4*)&xl[rowq * 132 + kk * 4];
            float xs[4] = {xv.x, xv.y, xv.z, xv.w};
            #pragma unroll
            for (int c = 0; c < 4; ++c) {
                float4 wv = *(const float4*)&Wc[(kk * 4 + c) * 16 + p * 4];
                acc0 += xs[c] * wv.x;
                acc1 += xs[c] * wv.y;
                acc2 += xs[c] * wv.z;
                acc3 += xs[c] * wv.w;
            }
        }

        const int row = rbase + rowq;
        ((float4*)xproj)[row * 4 + p] = make_float4(acc0, acc1, acc2, acc3);
    }
}

__global__ __launch_bounds__(64, 1) void qlstm_phase2(
    const float* __restrict__ xproj,
    const float* __restrict__ Wf, const float* __restrict__ Wi,
    const float* __restrict__ Wu, const float* __restrict__ Wo,
    float* __restrict__ out)
{
    const int tid = threadIdx.x;           // block = 1 wave of 64
    const int w = tid & 3;                 // wire
    const int b = (blockIdx.x * 64 + tid) >> 2;

    // Wh in NAMED scalars (no arrays anywhere on the loop-carried state)
    const float Wh00 = Wf[512 + w] * INV2PI, Wh01 = Wf[516 + w] * INV2PI,
                Wh02 = Wf[520 + w] * INV2PI, Wh03 = Wf[524 + w] * INV2PI;
    const float Wh10 = Wi[512 + w] * INV2PI, Wh11 = Wi[516 + w] * INV2PI,
                Wh12 = Wi[520 + w] * INV2PI, Wh13 = Wi[524 + w] * INV2PI;
    const float Wh20 = Wu[512 + w] * INV2PI, Wh21 = Wu[516 + w] * INV2PI,
                Wh22 = Wu[520 + w] * INV2PI, Wh23 = Wu[524 + w] * INV2PI;
    const float Wh30 = Wo[512 + w] * INV2PI, Wh31 = Wo[516 + w] * INV2PI,
                Wh32 = Wo[520 + w] * INV2PI, Wh33 = Wo[524 + w] * INV2PI;

    float h0 = 0.f, h1 = 0.f, h2 = 0.f, h3 = 0.f;
    float c = 0.f, hw = 0.f;

    const float4* __restrict__ xp4 = (const float4*)xproj;
    const size_t lbase = (size_t)b * 4 + w;      // element index at t=0
    #define XP_IDX(t) (lbase + (size_t)(t) * (B_DIM * 4))

    // 4-slot pipeline: each slot's load issued 4 steps before its use
    float4 p0 = xp4[XP_IDX(0)];
    float4 p1 = xp4[XP_IDX(1)];
    float4 p2 = xp4[XP_IDX(2)];
    float4 p3 = xp4[XP_IDX(3)];

    auto step = [&](const float4& xp, int t) {
        float a0 = (xp.x + h0 * Wh00 + h1 * Wh01) + (h2 * Wh02 + h3 * Wh03);
        float a1 = (xp.y + h0 * Wh10 + h1 * Wh11) + (h2 * Wh12 + h3 * Wh13);
        float a2 = (xp.z + h0 * Wh20 + h1 * Wh21) + (h2 * Wh22 + h3 * Wh23);
        float a3 = (xp.w + h0 * Wh30 + h1 * Wh31) + (h2 * Wh32 + h3 * Wh33);

        float z0, z1, z2, z3;
        {
            float cw = fast_cos_rev(a0);
            float c0 = quad_bcast<0>(cw), c1 = quad_bcast<1>(cw);
            float c2 = quad_bcast<2>(cw), c3 = quad_bcast<3>(cw);
            float p01 = c0 * c1, p012 = p01 * c2, p0123 = p012 * c3;
            float p123 = c1 * c2 * c3;
            z0 = (w == 0) ? p123 : (w == 1) ? p01 : (w == 2) ? p012 : p0123;
        }
        {
            float cw = fast_cos_rev(a1);
            float c0 = quad_bcast<0>(cw), c1 = quad_bcast<1>(cw);
            float c2 = quad_bcast<2>(cw), c3 = quad_bcast<3>(cw);
            float p01 = c0 * c1, p012 = p01 * c2, p0123 = p012 * c3;
            float p123 = c1 * c2 * c3;
            z1 = (w == 0) ? p123 : (w == 1) ? p01 : (w == 2) ? p012 : p0123;
        }
        {
            float cw = fast_cos_rev(a2);
            float c0 = quad_bcast<0>(cw), c1 = quad_bcast<1>(cw);
            float c2 = quad_bcast<2>(cw), c3 = quad_bcast<3>(cw);
            float p01 = c0 * c1, p012 = p01 * c2, p0123 = p012 * c3;
            float p123 = c1 * c2 * c3;
            z2 = (w == 0) ? p123 : (w == 1) ? p01 : (w == 2) ? p012 : p0123;
        }
        {
            float cw = fast_cos_rev(a3);
            float c0 = quad_bcast<0>(cw), c1 = quad_bcast<1>(cw);
            float c2 = quad_bcast<2>(cw), c3 = quad_bcast<3>(cw);
            float p01 = c0 * c1, p012 = p01 * c2, p0123 = p012 * c3;
            float p123 = c1 * c2 * c3;
            z3 = (w == 0) ? p123 : (w == 1) ? p01 : (w == 2) ? p012 : p0123;
        }

        float fg = fast_rcp(1.f + __expf(-z0));
        float ig = fast_rcp(1.f + __expf(-z1));
        float ug = 1.f - 2.f * fast_rcp(__expf(2.f * z2) + 1.f);
        float og = fast_rcp(1.f + __expf(-z3));

        c = fg * c + ig * ug;
        float ct = 1.f - 2.f * fast_rcp(__expf(2.f * c) + 1.f);
        hw = og * ct;

        out[(size_t)(t * B_DIM + b) * 4 + w] = hw;

        h0 = quad_bcast<0>(hw);
        h1 = quad_bcast<1>(hw);
        h2 = quad_bcast<2>(hw);
        h3 = quad_bcast<3>(hw);
    };

    #pragma unroll 1
    for (int t = 0; t < T_DIM; t += 4) {
        int n0 = (t + 4 < T_DIM) ? t + 4 : T_DIM - 1;
        int n1 = (t + 5 < T_DIM) ? t + 5 : T_DIM - 1;
        int n2 = (t + 6 < T_DIM) ? t + 6 : T_DIM - 1;
        int n3 = (t + 7 < T_DIM) ? t + 7 : T_DIM - 1;
        step(p0, t + 0); p0 = xp4[XP_IDX(n0)];
        step(p1, t + 1); p1 = xp4[XP_IDX(n1)];
        step(p2, t + 2); p2 = xp4[XP_IDX(n2)];
        step(p3, t + 3); p3 = xp4[XP_IDX(n3)];
    }
    #undef XP_IDX

    out[(size_t)T_DIM * B_DIM * 4 + (size_t)b * 4 + w] = hw;              // hx
    out[(size_t)T_DIM * B_DIM * 4 + B_DIM * 4 + (size_t)b * 4 + w] = c;   // cx
}

extern "C" void kernel_launch(void* const* d_in, const int* in_sizes, int n_in,
                              void* d_out, int out_size, void* d_ws, size_t ws_size,
                              hipStream_t stream) {
    const float* x   = (const float*)d_in[0];
    const float* Wf  = (const float*)d_in[1];
    const float* bf  = (const float*)d_in[2];
    const float* thf = (const float*)d_in[3];
    const float* Wi  = (const float*)d_in[4];
    const float* bi  = (const float*)d_in[5];
    const float* thi = (const float*)d_in[6];
    const float* Wu  = (const float*)d_in[7];
    const float* bu  = (const float*)d_in[8];
    const float* thu = (const float*)d_in[9];
    const float* Wo  = (const float*)d_in[10];
    const float* bo  = (const float*)d_in[11];
    const float* tho = (const float*)d_in[12];

    float* xproj = (float*)d_ws;            // 262144 * 16 * 4B = 16.8 MB
    float* out   = (float*)d_out;

    qlstm_phase1<<<NROW / 256, 256, 0, stream>>>(x, Wf, bf, thf, Wi, bi, thi,
                                                 Wu, bu, thu, Wo, bo, tho, xproj);
    qlstm_phase2<<<B_DIM * 4 / 64, 64, 0, stream>>>(xproj, Wf, Wi, Wu, Wo, out);
}